// Round 3
// baseline (289.991 us; speedup 1.0000x reference)
//
#include <hip/hip_runtime.h>

#define N_NODES 40000
#define N_EDGES 640000
#define CH 128
#define BN_EPS 1e-5f
#define NBLK_SCAN 157  // ceil(40000/256)

// ---------- ws layout (bytes) ----------
//  hbf:   [0, 10240000)            40000*128 bf16 (ushort)
//  deg:   [10240000, 10400000)     40000 i32
//  sums:  [10400000, 10401024)     256 f32 (contiguous after deg for one-shot zero)
//  offs:  [10401024, 10561024)     40000 i32
//  dinv:  [10561024, 10721024)     40000 f32
//  bases: [10721024, 10721664)     157 i32 (padded)
//  csr:   [10721664, 13281664)     640000 i32
#define FAST_WS_BYTES 13281664ull

__device__ __forceinline__ float bf_lo(unsigned u) { return __uint_as_float(u << 16); }
__device__ __forceinline__ float bf_hi(unsigned u) { return __uint_as_float(u & 0xffff0000u); }
__device__ __forceinline__ unsigned short f2bf(float f) {
    unsigned u = __float_as_uint(f);
    unsigned r = 0x7fffu + ((u >> 16) & 1u);
    return (unsigned short)((u + r) >> 16);
}
__device__ __forceinline__ unsigned pack2bf(float a, float b) {
    return (unsigned)f2bf(a) | ((unsigned)f2bf(b) << 16);
}

__global__ __launch_bounds__(256) void zero_kernel(int* __restrict__ p, int n) {
    int i = blockIdx.x * blockDim.x + threadIdx.x;
    if (i < n) p[i] = 0;
}

__global__ __launch_bounds__(256) void deg_kernel(const int* __restrict__ dst,
                                                  int* __restrict__ deg) {
    int e = blockIdx.x * blockDim.x + threadIdx.x;
    if (e < N_EDGES) atomicAdd(&deg[dst[e]], 1);
}

// per-block exclusive scan of deg -> offs (block-local), block totals -> bases[]
// also computes dinv = rsqrt(deg+1)
__global__ __launch_bounds__(256) void scan_a(const int* __restrict__ deg,
                                              int* __restrict__ offs,
                                              int* __restrict__ bases,
                                              float* __restrict__ dinv) {
    __shared__ int tmp[256];
    int g = blockIdx.x * 256 + threadIdx.x;
    int v = (g < N_NODES) ? deg[g] : 0;
    tmp[threadIdx.x] = v;
    __syncthreads();
    for (int off = 1; off < 256; off <<= 1) {
        int t = (threadIdx.x >= off) ? tmp[threadIdx.x - off] : 0;
        __syncthreads();
        tmp[threadIdx.x] += t;
        __syncthreads();
    }
    if (g < N_NODES) {
        offs[g] = tmp[threadIdx.x] - v;  // local exclusive
        dinv[g] = rsqrtf((float)v + 1.0f);
    }
    if (threadIdx.x == 255) bases[blockIdx.x] = tmp[255];
}

__global__ __launch_bounds__(256) void scan_b(int* __restrict__ bases) {
    __shared__ int tmp[256];
    int v = (threadIdx.x < NBLK_SCAN) ? bases[threadIdx.x] : 0;
    tmp[threadIdx.x] = v;
    __syncthreads();
    for (int off = 1; off < 256; off <<= 1) {
        int t = (threadIdx.x >= off) ? tmp[threadIdx.x - off] : 0;
        __syncthreads();
        tmp[threadIdx.x] += t;
        __syncthreads();
    }
    if (threadIdx.x < NBLK_SCAN) bases[threadIdx.x] = tmp[threadIdx.x] - v;
}

__global__ __launch_bounds__(256) void fill_kernel(const int* __restrict__ src,
                                                   const int* __restrict__ dst,
                                                   const int* __restrict__ bases,
                                                   int* __restrict__ offs,
                                                   int* __restrict__ csr) {
    int e = blockIdx.x * blockDim.x + threadIdx.x;
    if (e >= N_EDGES) return;
    int d = dst[e];
    int pos = bases[d >> 8] + atomicAdd(&offs[d], 1);
    csr[pos] = src[e];
}

// x @ W -> bf16 h. 32 rows/block; W in LDS as packed bf16 (32 KB), x fp32 (16 KB).
#define MM_ROWS 32
__global__ __launch_bounds__(256) void matmul_kernel(const float* __restrict__ x,
                                                     const float* __restrict__ W,
                                                     unsigned short* __restrict__ hbf) {
    __shared__ unsigned Wsb[CH * CH / 2];   // 32 KB: row k = 64 uints (2 ch each)
    __shared__ float xs[MM_ROWS][CH];       // 16 KB
    int t = threadIdx.x;
    // load + pack W: each thread 16 float4 -> 16 uint2
    for (int i = t; i < CH * CH / 4; i += 256) {
        float4 w = ((const float4*)W)[i];
        uint2 p;
        p.x = pack2bf(w.x, w.y);
        p.y = pack2bf(w.z, w.w);
        ((uint2*)Wsb)[i] = p;
    }
    size_t row0 = (size_t)blockIdx.x * MM_ROWS;
    for (int i = t; i < MM_ROWS * CH / 4; i += 256)
        ((float4*)xs)[i] = ((const float4*)(x + row0 * CH))[i];
    __syncthreads();
    int ch4 = t & 31;   // float4 column group
    int rg = t >> 5;    // row group [0,8)
    float4 acc0 = {0,0,0,0}, acc1 = {0,0,0,0}, acc2 = {0,0,0,0}, acc3 = {0,0,0,0};
#pragma unroll 4
    for (int k = 0; k < CH; ++k) {
        uint2 wp = ((const uint2*)Wsb)[k * 32 + ch4];
        float w0 = bf_lo(wp.x), w1 = bf_hi(wp.x), w2 = bf_lo(wp.y), w3 = bf_hi(wp.y);
        float x0 = xs[rg][k];
        float x1 = xs[rg + 8][k];
        float x2 = xs[rg + 16][k];
        float x3 = xs[rg + 24][k];
        acc0.x += x0 * w0; acc0.y += x0 * w1; acc0.z += x0 * w2; acc0.w += x0 * w3;
        acc1.x += x1 * w0; acc1.y += x1 * w1; acc1.z += x1 * w2; acc1.w += x1 * w3;
        acc2.x += x2 * w0; acc2.y += x2 * w1; acc2.z += x2 * w2; acc2.w += x2 * w3;
        acc3.x += x3 * w0; acc3.y += x3 * w1; acc3.z += x3 * w2; acc3.w += x3 * w3;
    }
    uint2 o;
    o.x = pack2bf(acc0.x, acc0.y); o.y = pack2bf(acc0.z, acc0.w);
    ((uint2*)(hbf + (row0 + rg) * CH))[ch4] = o;
    o.x = pack2bf(acc1.x, acc1.y); o.y = pack2bf(acc1.z, acc1.w);
    ((uint2*)(hbf + (row0 + rg + 8) * CH))[ch4] = o;
    o.x = pack2bf(acc2.x, acc2.y); o.y = pack2bf(acc2.z, acc2.w);
    ((uint2*)(hbf + (row0 + rg + 16) * CH))[ch4] = o;
    o.x = pack2bf(acc3.x, acc3.y); o.y = pack2bf(acc3.z, acc3.w);
    ((uint2*)(hbf + (row0 + rg + 24) * CH))[ch4] = o;
}

// one wave per node (grid-stride): two 32-lane halves process alternate edges,
// each lane covers 4 channels (8 B bf16 load). BN partial sums fused.
#define AGG_BLOCKS 640
__global__ __launch_bounds__(256) void aggregate_kernel(const int* __restrict__ csr,
                                                        const int* __restrict__ offs,
                                                        const int* __restrict__ bases,
                                                        const unsigned short* __restrict__ hbf,
                                                        const float* __restrict__ dinv,
                                                        const float* __restrict__ b,
                                                        float* __restrict__ out,
                                                        float* __restrict__ sums) {
    __shared__ float bsum[CH], bsq[CH];
    int t = threadIdx.x;
    if (t < CH) { bsum[t] = 0.0f; bsq[t] = 0.0f; }
    __syncthreads();
    int lane = t & 63;
    int half = lane >> 5;
    int cl = lane & 31;
    int gwave = blockIdx.x * 4 + (t >> 6);
    int nWaves = gridDim.x * 4;
    float4 bv = ((const float4*)b)[cl];
    const uint2* h2 = (const uint2*)hbf;  // row = 32 uint2
    float ps0 = 0, ps1 = 0, ps2 = 0, ps3 = 0;
    float pq0 = 0, pq1 = 0, pq2 = 0, pq3 = 0;
    for (int n = gwave; n < N_NODES; n += nWaves) {
        int end = bases[n >> 8] + offs[n];
        int beg = (n == 0) ? 0 : (bases[(n - 1) >> 8] + offs[n - 1]);
        float dn = dinv[n];
        float a0 = 0, a1 = 0, a2 = 0, a3 = 0;
        for (int j = beg + half; j < end; j += 2) {
            int s = csr[j];
            float ds = dinv[s];
            uint2 raw = h2[(size_t)s * 32 + cl];
            a0 += bf_lo(raw.x) * ds;
            a1 += bf_hi(raw.x) * ds;
            a2 += bf_lo(raw.y) * ds;
            a3 += bf_hi(raw.y) * ds;
        }
        a0 += __shfl_xor(a0, 32, 64);
        a1 += __shfl_xor(a1, 32, 64);
        a2 += __shfl_xor(a2, 32, 64);
        a3 += __shfl_xor(a3, 32, 64);
        if (half == 0) {
            uint2 raw = h2[(size_t)n * 32 + cl];
            float s2 = dn * dn;
            float o0 = a0 * dn + bf_lo(raw.x) * s2 + bv.x;
            float o1 = a1 * dn + bf_hi(raw.x) * s2 + bv.y;
            float o2 = a2 * dn + bf_lo(raw.y) * s2 + bv.z;
            float o3 = a3 * dn + bf_hi(raw.y) * s2 + bv.w;
            float4 o = {o0, o1, o2, o3};
            ((float4*)(out + (size_t)n * CH))[cl] = o;
            ps0 += o0; pq0 += o0 * o0;
            ps1 += o1; pq1 += o1 * o1;
            ps2 += o2; pq2 += o2 * o2;
            ps3 += o3; pq3 += o3 * o3;
        }
    }
    if (half == 0) {
        int c0 = cl * 4;
        atomicAdd(&bsum[c0 + 0], ps0); atomicAdd(&bsq[c0 + 0], pq0);
        atomicAdd(&bsum[c0 + 1], ps1); atomicAdd(&bsq[c0 + 1], pq1);
        atomicAdd(&bsum[c0 + 2], ps2); atomicAdd(&bsq[c0 + 2], pq2);
        atomicAdd(&bsum[c0 + 3], ps3); atomicAdd(&bsq[c0 + 3], pq3);
    }
    __syncthreads();
    if (t < CH) atomicAdd(&sums[t], bsum[t]);
    else atomicAdd(&sums[t], bsq[t - CH]);
}

__global__ __launch_bounds__(256) void bn_relu_kernel(float* __restrict__ out,
                                                      const float* __restrict__ sums,
                                                      const float* __restrict__ gamma,
                                                      const float* __restrict__ beta) {
    int i = blockIdx.x * blockDim.x + threadIdx.x;
    if (i >= N_NODES * CH / 4) return;
    int c0 = (i & 31) * 4;
    const float invN = 1.0f / (float)N_NODES;
    float4 v = ((float4*)out)[i];
    float r[4] = {v.x, v.y, v.z, v.w};
#pragma unroll
    for (int j = 0; j < 4; ++j) {
        int c = c0 + j;
        float mean = sums[c] * invN;
        float var = sums[CH + c] * invN - mean * mean;
        float scale = gamma[c] * rsqrtf(var + BN_EPS);
        float val = (r[j] - mean) * scale + beta[c];
        r[j] = val > 0.0f ? val : 0.0f;
    }
    v.x = r[0]; v.y = r[1]; v.z = r[2]; v.w = r[3];
    ((float4*)out)[i] = v;
}

extern "C" void kernel_launch(void* const* d_in, const int* in_sizes, int n_in,
                              void* d_out, int out_size, void* d_ws, size_t ws_size,
                              hipStream_t stream) {
    const float* x = (const float*)d_in[0];
    const int* ei = (const int*)d_in[1];
    const float* W = (const float*)d_in[2];
    const float* b = (const float*)d_in[3];
    const float* gamma = (const float*)d_in[4];
    const float* beta = (const float*)d_in[5];
    float* out = (float*)d_out;
    const int* src = ei;
    const int* dst = ei + N_EDGES;
    char* ws = (char*)d_ws;

    unsigned short* hbf = (unsigned short*)ws;
    int* deg = (int*)(ws + 10240000);
    float* sums = (float*)(ws + 10400000);
    int* offs = (int*)(ws + 10401024);
    float* dinv = (float*)(ws + 10561024);
    int* bases = (int*)(ws + 10721024);
    int* csr = (int*)(ws + 10721664);

    // zero deg (40000 i32) + sums (256 f32) in one contiguous pass
    zero_kernel<<<(40256 + 255) / 256, 256, 0, stream>>>(deg, 40256);
    deg_kernel<<<(N_EDGES + 255) / 256, 256, 0, stream>>>(dst, deg);
    scan_a<<<NBLK_SCAN, 256, 0, stream>>>(deg, offs, bases, dinv);
    scan_b<<<1, 256, 0, stream>>>(bases);
    fill_kernel<<<(N_EDGES + 255) / 256, 256, 0, stream>>>(src, dst, bases, offs, csr);
    matmul_kernel<<<N_NODES / MM_ROWS, 256, 0, stream>>>(x, W, hbf);
    aggregate_kernel<<<AGG_BLOCKS, 256, 0, stream>>>(csr, offs, bases, hbf, dinv, b, out, sums);
    bn_relu_kernel<<<(N_NODES * CH / 4 + 255) / 256, 256, 0, stream>>>(out, sums, gamma, beta);
}

// Round 4
// 262.774 us; speedup vs baseline: 1.1036x; 1.1036x over previous
//
#include <hip/hip_runtime.h>

#define N_NODES 40000
#define N_EDGES 640000
#define CH 128
#define BN_EPS 1e-5f
#define NBLK_SCAN 157  // ceil(40000/256)

// ---------- ws layout (bytes) ----------
//  hbf:   [0, 10240000)             40000*128 bf16
//  deg:   [10240000, 10400000)      40000 i32
//  sums8: [10400000, 10408192)      8 copies x 256 f32 (contiguous after deg for one-shot zero)
//  offs:  [10408192, 10568192)      40000 i32
//  dinv:  [10568192, 10728192)      40000 f32
//  bases: [10728192, 10728832)      157 i32 (padded)
//  csr64: [10728832, 15848832)      640000 uint2 {src, bitcast(dinv[src])}
#define WS_NEED 15848832ull

__device__ __forceinline__ float bf_lo(unsigned u) { return __uint_as_float(u << 16); }
__device__ __forceinline__ float bf_hi(unsigned u) { return __uint_as_float(u & 0xffff0000u); }
__device__ __forceinline__ unsigned short f2bf(float f) {
    unsigned u = __float_as_uint(f);
    unsigned r = 0x7fffu + ((u >> 16) & 1u);
    return (unsigned short)((u + r) >> 16);
}
__device__ __forceinline__ unsigned pack2bf(float a, float b) {
    return (unsigned)f2bf(a) | ((unsigned)f2bf(b) << 16);
}

__global__ __launch_bounds__(256) void zero_kernel(int* __restrict__ p, int n) {
    int i = blockIdx.x * blockDim.x + threadIdx.x;
    if (i < n) p[i] = 0;
}

__global__ __launch_bounds__(256) void deg_kernel(const int* __restrict__ dst,
                                                  int* __restrict__ deg) {
    int e = blockIdx.x * blockDim.x + threadIdx.x;
    if (e < N_EDGES) atomicAdd(&deg[dst[e]], 1);
}

// per-block exclusive scan of deg -> offs (block-local), block totals -> bases[]; dinv too
__global__ __launch_bounds__(256) void scan_a(const int* __restrict__ deg,
                                              int* __restrict__ offs,
                                              int* __restrict__ bases,
                                              float* __restrict__ dinv) {
    __shared__ int tmp[256];
    int g = blockIdx.x * 256 + threadIdx.x;
    int v = (g < N_NODES) ? deg[g] : 0;
    tmp[threadIdx.x] = v;
    __syncthreads();
    for (int off = 1; off < 256; off <<= 1) {
        int t = (threadIdx.x >= off) ? tmp[threadIdx.x - off] : 0;
        __syncthreads();
        tmp[threadIdx.x] += t;
        __syncthreads();
    }
    if (g < N_NODES) {
        offs[g] = tmp[threadIdx.x] - v;  // local exclusive
        dinv[g] = rsqrtf((float)v + 1.0f);
    }
    if (threadIdx.x == 255) bases[blockIdx.x] = tmp[255];
}

__global__ __launch_bounds__(256) void scan_b(int* __restrict__ bases) {
    __shared__ int tmp[256];
    int v = (threadIdx.x < NBLK_SCAN) ? bases[threadIdx.x] : 0;
    tmp[threadIdx.x] = v;
    __syncthreads();
    for (int off = 1; off < 256; off <<= 1) {
        int t = (threadIdx.x >= off) ? tmp[threadIdx.x - off] : 0;
        __syncthreads();
        tmp[threadIdx.x] += t;
        __syncthreads();
    }
    if (threadIdx.x < NBLK_SCAN) bases[threadIdx.x] = tmp[threadIdx.x] - v;
}

// bucket fill with fused payload {src, dinv[src]}
__global__ __launch_bounds__(256) void fill_kernel(const int* __restrict__ src,
                                                   const int* __restrict__ dst,
                                                   const int* __restrict__ bases,
                                                   const float* __restrict__ dinv,
                                                   int* __restrict__ offs,
                                                   uint2* __restrict__ csr64) {
    int e = blockIdx.x * blockDim.x + threadIdx.x;
    if (e >= N_EDGES) return;
    int d = dst[e];
    int s = src[e];
    int pos = bases[d >> 8] + atomicAdd(&offs[d], 1);
    uint2 p;
    p.x = (unsigned)s;
    p.y = __float_as_uint(dinv[s]);
    csr64[pos] = p;
}

// x @ W -> bf16 h. 32 rows/block; W in LDS as packed bf16 (32 KB), x fp32 (16 KB).
#define MM_ROWS 32
__global__ __launch_bounds__(256) void matmul_kernel(const float* __restrict__ x,
                                                     const float* __restrict__ W,
                                                     unsigned short* __restrict__ hbf) {
    __shared__ unsigned Wsb[CH * CH / 2];
    __shared__ float xs[MM_ROWS][CH];
    int t = threadIdx.x;
    for (int i = t; i < CH * CH / 4; i += 256) {
        float4 w = ((const float4*)W)[i];
        uint2 p;
        p.x = pack2bf(w.x, w.y);
        p.y = pack2bf(w.z, w.w);
        ((uint2*)Wsb)[i] = p;
    }
    size_t row0 = (size_t)blockIdx.x * MM_ROWS;
    for (int i = t; i < MM_ROWS * CH / 4; i += 256)
        ((float4*)xs)[i] = ((const float4*)(x + row0 * CH))[i];
    __syncthreads();
    int ch4 = t & 31;
    int rg = t >> 5;
    float4 acc0 = {0,0,0,0}, acc1 = {0,0,0,0}, acc2 = {0,0,0,0}, acc3 = {0,0,0,0};
#pragma unroll 4
    for (int k = 0; k < CH; ++k) {
        uint2 wp = ((const uint2*)Wsb)[k * 32 + ch4];
        float w0 = bf_lo(wp.x), w1 = bf_hi(wp.x), w2 = bf_lo(wp.y), w3 = bf_hi(wp.y);
        float x0 = xs[rg][k];
        float x1 = xs[rg + 8][k];
        float x2 = xs[rg + 16][k];
        float x3 = xs[rg + 24][k];
        acc0.x += x0 * w0; acc0.y += x0 * w1; acc0.z += x0 * w2; acc0.w += x0 * w3;
        acc1.x += x1 * w0; acc1.y += x1 * w1; acc1.z += x1 * w2; acc1.w += x1 * w3;
        acc2.x += x2 * w0; acc2.y += x2 * w1; acc2.z += x2 * w2; acc2.w += x2 * w3;
        acc3.x += x3 * w0; acc3.y += x3 * w1; acc3.z += x3 * w2; acc3.w += x3 * w3;
    }
    uint2 o;
    o.x = pack2bf(acc0.x, acc0.y); o.y = pack2bf(acc0.z, acc0.w);
    ((uint2*)(hbf + (row0 + rg) * CH))[ch4] = o;
    o.x = pack2bf(acc1.x, acc1.y); o.y = pack2bf(acc1.z, acc1.w);
    ((uint2*)(hbf + (row0 + rg + 8) * CH))[ch4] = o;
    o.x = pack2bf(acc2.x, acc2.y); o.y = pack2bf(acc2.z, acc2.w);
    ((uint2*)(hbf + (row0 + rg + 16) * CH))[ch4] = o;
    o.x = pack2bf(acc3.x, acc3.y); o.y = pack2bf(acc3.z, acc3.w);
    ((uint2*)(hbf + (row0 + rg + 24) * CH))[ch4] = o;
}

// one wave per node (10000 blocks x 4 waves). Two 32-lane halves take alternate
// edges; lane covers 4 channels (8 B bf16). BN partials: LDS -> 8-way replicated sums.
__global__ __launch_bounds__(256) void aggregate_kernel(const uint2* __restrict__ csr64,
                                                        const int* __restrict__ offs,
                                                        const int* __restrict__ bases,
                                                        const unsigned short* __restrict__ hbf,
                                                        const float* __restrict__ dinv,
                                                        const float* __restrict__ b,
                                                        float* __restrict__ out,
                                                        float* __restrict__ sums8) {
    __shared__ float bsum[CH], bsq[CH];
    int t = threadIdx.x;
    if (t < CH) { bsum[t] = 0.0f; bsq[t] = 0.0f; }
    __syncthreads();
    int n = blockIdx.x * 4 + (t >> 6);
    int lane = t & 63;
    int half = lane >> 5;
    int cl = lane & 31;
    int end = bases[n >> 8] + offs[n];
    int beg = (n == 0) ? 0 : (bases[(n - 1) >> 8] + offs[n - 1]);
    float dn = dinv[n];
    const uint2* h2 = (const uint2*)hbf;  // row = 32 uint2
    float a0 = 0, a1 = 0, a2 = 0, a3 = 0;
    for (int j = beg + half; j < end; j += 2) {
        uint2 e = csr64[j];
        float ds = __uint_as_float(e.y);
        uint2 raw = h2[(size_t)e.x * 32 + cl];
        a0 += bf_lo(raw.x) * ds;
        a1 += bf_hi(raw.x) * ds;
        a2 += bf_lo(raw.y) * ds;
        a3 += bf_hi(raw.y) * ds;
    }
    a0 += __shfl_xor(a0, 32, 64);
    a1 += __shfl_xor(a1, 32, 64);
    a2 += __shfl_xor(a2, 32, 64);
    a3 += __shfl_xor(a3, 32, 64);
    if (half == 0) {
        uint2 raw = h2[(size_t)n * 32 + cl];
        float4 bv = ((const float4*)b)[cl];
        float s2 = dn * dn;
        float o0 = a0 * dn + bf_lo(raw.x) * s2 + bv.x;
        float o1 = a1 * dn + bf_hi(raw.x) * s2 + bv.y;
        float o2 = a2 * dn + bf_lo(raw.y) * s2 + bv.z;
        float o3 = a3 * dn + bf_hi(raw.y) * s2 + bv.w;
        float4 o = {o0, o1, o2, o3};
        ((float4*)(out + (size_t)n * CH))[cl] = o;
        int c0 = cl * 4;
        atomicAdd(&bsum[c0 + 0], o0); atomicAdd(&bsq[c0 + 0], o0 * o0);
        atomicAdd(&bsum[c0 + 1], o1); atomicAdd(&bsq[c0 + 1], o1 * o1);
        atomicAdd(&bsum[c0 + 2], o2); atomicAdd(&bsq[c0 + 2], o2 * o2);
        atomicAdd(&bsum[c0 + 3], o3); atomicAdd(&bsq[c0 + 3], o3 * o3);
    }
    __syncthreads();
    float* dst8 = sums8 + (blockIdx.x & 7) * 256;
    atomicAdd(&dst8[t], (t < CH) ? bsum[t] : bsq[t - CH]);
}

__global__ __launch_bounds__(256) void bn_relu_kernel(float* __restrict__ out,
                                                      const float* __restrict__ sums8,
                                                      const float* __restrict__ gamma,
                                                      const float* __restrict__ beta) {
    __shared__ float sc[CH], sh[CH];
    int t = threadIdx.x;
    if (t < CH) {
        float s = 0.0f, q = 0.0f;
#pragma unroll
        for (int k = 0; k < 8; ++k) {
            s += sums8[k * 256 + t];
            q += sums8[k * 256 + CH + t];
        }
        const float invN = 1.0f / (float)N_NODES;
        float mean = s * invN;
        float var = q * invN - mean * mean;
        float scale = gamma[t] * rsqrtf(var + BN_EPS);
        sc[t] = scale;
        sh[t] = beta[t] - mean * scale;
    }
    __syncthreads();
    int i = blockIdx.x * 256 + t;  // float4 index; grid covers exactly N*CH/4
    int c0 = (i & 31) * 4;
    float4 v = ((float4*)out)[i];
    float r0 = v.x * sc[c0] + sh[c0];
    float r1 = v.y * sc[c0 + 1] + sh[c0 + 1];
    float r2 = v.z * sc[c0 + 2] + sh[c0 + 2];
    float r3 = v.w * sc[c0 + 3] + sh[c0 + 3];
    v.x = r0 > 0.0f ? r0 : 0.0f;
    v.y = r1 > 0.0f ? r1 : 0.0f;
    v.z = r2 > 0.0f ? r2 : 0.0f;
    v.w = r3 > 0.0f ? r3 : 0.0f;
    ((float4*)out)[i] = v;
}

extern "C" void kernel_launch(void* const* d_in, const int* in_sizes, int n_in,
                              void* d_out, int out_size, void* d_ws, size_t ws_size,
                              hipStream_t stream) {
    const float* x = (const float*)d_in[0];
    const int* ei = (const int*)d_in[1];
    const float* W = (const float*)d_in[2];
    const float* b = (const float*)d_in[3];
    const float* gamma = (const float*)d_in[4];
    const float* beta = (const float*)d_in[5];
    float* out = (float*)d_out;
    const int* src = ei;
    const int* dst = ei + N_EDGES;
    char* ws = (char*)d_ws;

    unsigned short* hbf = (unsigned short*)ws;
    int* deg = (int*)(ws + 10240000);
    float* sums8 = (float*)(ws + 10400000);
    int* offs = (int*)(ws + 10408192);
    float* dinv = (float*)(ws + 10568192);
    int* bases = (int*)(ws + 10728192);
    uint2* csr64 = (uint2*)(ws + 10728832);

    // zero deg (40000 i32) + sums8 (2048 f32) in one contiguous pass
    zero_kernel<<<(42048 + 255) / 256, 256, 0, stream>>>(deg, 42048);
    deg_kernel<<<(N_EDGES + 255) / 256, 256, 0, stream>>>(dst, deg);
    scan_a<<<NBLK_SCAN, 256, 0, stream>>>(deg, offs, bases, dinv);
    scan_b<<<1, 256, 0, stream>>>(bases);
    fill_kernel<<<(N_EDGES + 255) / 256, 256, 0, stream>>>(src, dst, bases, dinv, offs, csr64);
    matmul_kernel<<<N_NODES / MM_ROWS, 256, 0, stream>>>(x, W, hbf);
    aggregate_kernel<<<N_NODES / 4, 256, 0, stream>>>(csr64, offs, bases, hbf, dinv, b, out, sums8);
    bn_relu_kernel<<<N_NODES * CH / 4 / 256, 256, 0, stream>>>(out, sums8, gamma, beta);
}

// Round 5
// 250.841 us; speedup vs baseline: 1.1561x; 1.0476x over previous
//
#include <hip/hip_runtime.h>

#define N_NODES 40000
#define N_EDGES 640000
#define CH 128
#define BN_EPS 1e-5f
#define NBLK_SCAN 157  // ceil(40000/256)

// ---------- ws layout (bytes) ----------
//  hbf:   [0, 10240000)             40000*128 bf16
//  deg:   [10240000, 10400000)      40000 i32
//  sums8: [10400000, 10408192)      8 copies x 256 f32 (contiguous after deg: one memset)
//  offs:  [10408192, 10568192)      40000 i32
//  dinv:  [10568192, 10728192)      40000 f32
//  bases: [10728192, 10728832)      157 i32 (padded)
//  csr64: [10728832, 15848832)      640000 uint2 {src, bitcast(dinv[src])}

__device__ __forceinline__ float bf_lo(unsigned u) { return __uint_as_float(u << 16); }
__device__ __forceinline__ float bf_hi(unsigned u) { return __uint_as_float(u & 0xffff0000u); }
__device__ __forceinline__ unsigned short f2bf(float f) {
    unsigned u = __float_as_uint(f);
    unsigned r = 0x7fffu + ((u >> 16) & 1u);
    return (unsigned short)((u + r) >> 16);
}
__device__ __forceinline__ unsigned pack2bf(float a, float b) {
    return (unsigned)f2bf(a) | ((unsigned)f2bf(b) << 16);
}

__global__ __launch_bounds__(256) void deg_kernel(const int* __restrict__ dst,
                                                  int* __restrict__ deg) {
    int e = blockIdx.x * blockDim.x + threadIdx.x;
    if (e < N_EDGES) atomicAdd(&deg[dst[e]], 1);
}

// per-block exclusive scan of deg -> offs (block-local), block totals -> bases[]; dinv too
__global__ __launch_bounds__(256) void scan_a(const int* __restrict__ deg,
                                              int* __restrict__ offs,
                                              int* __restrict__ bases,
                                              float* __restrict__ dinv) {
    __shared__ int tmp[256];
    int g = blockIdx.x * 256 + threadIdx.x;
    int v = (g < N_NODES) ? deg[g] : 0;
    tmp[threadIdx.x] = v;
    __syncthreads();
    for (int off = 1; off < 256; off <<= 1) {
        int t = (threadIdx.x >= off) ? tmp[threadIdx.x - off] : 0;
        __syncthreads();
        tmp[threadIdx.x] += t;
        __syncthreads();
    }
    if (g < N_NODES) {
        offs[g] = tmp[threadIdx.x] - v;  // local exclusive
        dinv[g] = rsqrtf((float)v + 1.0f);
    }
    if (threadIdx.x == 255) bases[blockIdx.x] = tmp[255];
}

__global__ __launch_bounds__(256) void scan_b(int* __restrict__ bases) {
    __shared__ int tmp[256];
    int v = (threadIdx.x < NBLK_SCAN) ? bases[threadIdx.x] : 0;
    tmp[threadIdx.x] = v;
    __syncthreads();
    for (int off = 1; off < 256; off <<= 1) {
        int t = (threadIdx.x >= off) ? tmp[threadIdx.x - off] : 0;
        __syncthreads();
        tmp[threadIdx.x] += t;
        __syncthreads();
    }
    if (threadIdx.x < NBLK_SCAN) bases[threadIdx.x] = tmp[threadIdx.x] - v;
}

// bucket fill with fused payload {src, dinv[src]}
__global__ __launch_bounds__(256) void fill_kernel(const int* __restrict__ src,
                                                   const int* __restrict__ dst,
                                                   const int* __restrict__ bases,
                                                   const float* __restrict__ dinv,
                                                   int* __restrict__ offs,
                                                   uint2* __restrict__ csr64) {
    int e = blockIdx.x * blockDim.x + threadIdx.x;
    if (e >= N_EDGES) return;
    int d = dst[e];
    int s = src[e];
    int pos = bases[d >> 8] + atomicAdd(&offs[d], 1);
    uint2 p;
    p.x = (unsigned)s;
    p.y = __float_as_uint(dinv[s]);
    csr64[pos] = p;
}

// x @ W -> bf16 h. 32 rows/block; W in LDS as packed bf16 (32 KB), x fp32 (16 KB).
#define MM_ROWS 32
__global__ __launch_bounds__(256) void matmul_kernel(const float* __restrict__ x,
                                                     const float* __restrict__ W,
                                                     unsigned short* __restrict__ hbf) {
    __shared__ unsigned Wsb[CH * CH / 2];
    __shared__ float xs[MM_ROWS][CH];
    int t = threadIdx.x;
    for (int i = t; i < CH * CH / 4; i += 256) {
        float4 w = ((const float4*)W)[i];
        uint2 p;
        p.x = pack2bf(w.x, w.y);
        p.y = pack2bf(w.z, w.w);
        ((uint2*)Wsb)[i] = p;
    }
    size_t row0 = (size_t)blockIdx.x * MM_ROWS;
    for (int i = t; i < MM_ROWS * CH / 4; i += 256)
        ((float4*)xs)[i] = ((const float4*)(x + row0 * CH))[i];
    __syncthreads();
    int ch4 = t & 31;
    int rg = t >> 5;
    float4 acc0 = {0,0,0,0}, acc1 = {0,0,0,0}, acc2 = {0,0,0,0}, acc3 = {0,0,0,0};
#pragma unroll 4
    for (int k = 0; k < CH; ++k) {
        uint2 wp = ((const uint2*)Wsb)[k * 32 + ch4];
        float w0 = bf_lo(wp.x), w1 = bf_hi(wp.x), w2 = bf_lo(wp.y), w3 = bf_hi(wp.y);
        float x0 = xs[rg][k];
        float x1 = xs[rg + 8][k];
        float x2 = xs[rg + 16][k];
        float x3 = xs[rg + 24][k];
        acc0.x += x0 * w0; acc0.y += x0 * w1; acc0.z += x0 * w2; acc0.w += x0 * w3;
        acc1.x += x1 * w0; acc1.y += x1 * w1; acc1.z += x1 * w2; acc1.w += x1 * w3;
        acc2.x += x2 * w0; acc2.y += x2 * w1; acc2.z += x2 * w2; acc2.w += x2 * w3;
        acc3.x += x3 * w0; acc3.y += x3 * w1; acc3.z += x3 * w2; acc3.w += x3 * w3;
    }
    uint2 o;
    o.x = pack2bf(acc0.x, acc0.y); o.y = pack2bf(acc0.z, acc0.w);
    ((uint2*)(hbf + (row0 + rg) * CH))[ch4] = o;
    o.x = pack2bf(acc1.x, acc1.y); o.y = pack2bf(acc1.z, acc1.w);
    ((uint2*)(hbf + (row0 + rg + 8) * CH))[ch4] = o;
    o.x = pack2bf(acc2.x, acc2.y); o.y = pack2bf(acc2.z, acc2.w);
    ((uint2*)(hbf + (row0 + rg + 16) * CH))[ch4] = o;
    o.x = pack2bf(acc3.x, acc3.y); o.y = pack2bf(acc3.z, acc3.w);
    ((uint2*)(hbf + (row0 + rg + 24) * CH))[ch4] = o;
}

// one wave per node (10000 blocks x 4 waves). Edge payloads preloaded coalesced;
// 4 quarters x 16 lanes: each iteration gathers 4 full bf16 rows (1 KB) in ONE
// VMEM instruction with addresses from register shuffles (no dependent chain).
__global__ __launch_bounds__(256) void aggregate_kernel(const uint2* __restrict__ csr64,
                                                        const int* __restrict__ offs,
                                                        const int* __restrict__ bases,
                                                        const unsigned short* __restrict__ hbf,
                                                        const float* __restrict__ dinv,
                                                        const float* __restrict__ b,
                                                        float* __restrict__ out,
                                                        float* __restrict__ sums8) {
    __shared__ float bsum[CH], bsq[CH];
    int t = threadIdx.x;
    if (t < CH) { bsum[t] = 0.0f; bsq[t] = 0.0f; }
    __syncthreads();
    int n = blockIdx.x * 4 + (t >> 6);
    int lane = t & 63;
    int quarter = lane >> 4;
    int ql = lane & 15;
    int end = bases[n >> 8] + offs[n];
    int beg = (n == 0) ? 0 : (bases[(n - 1) >> 8] + offs[n - 1]);
    float dn = dinv[n];
    const uint4* h4 = (const uint4*)hbf;  // row = 16 uint4 (256 B)
    float a0 = 0, a1 = 0, a2 = 0, a3 = 0, a4 = 0, a5 = 0, a6 = 0, a7 = 0;
    for (int base = beg; base < end; base += 64) {
        int m = end - base;
        if (m > 64) m = 64;
        uint2 ep;
        ep.x = 0; ep.y = 0;
        if (lane < m) ep = csr64[base + lane];
        for (int jj = 0; jj < m; jj += 4) {
            int e = jj + quarter;
            unsigned sx = (unsigned)__shfl((int)ep.x, e, 64);
            float ds = __uint_as_float(__shfl((int)ep.y, e, 64));
            if (e >= m) { sx = 0; ds = 0.0f; }
            uint4 raw = h4[(size_t)sx * 16 + ql];
            a0 += bf_lo(raw.x) * ds; a1 += bf_hi(raw.x) * ds;
            a2 += bf_lo(raw.y) * ds; a3 += bf_hi(raw.y) * ds;
            a4 += bf_lo(raw.z) * ds; a5 += bf_hi(raw.z) * ds;
            a6 += bf_lo(raw.w) * ds; a7 += bf_hi(raw.w) * ds;
        }
    }
    a0 += __shfl_xor(a0, 16, 64); a0 += __shfl_xor(a0, 32, 64);
    a1 += __shfl_xor(a1, 16, 64); a1 += __shfl_xor(a1, 32, 64);
    a2 += __shfl_xor(a2, 16, 64); a2 += __shfl_xor(a2, 32, 64);
    a3 += __shfl_xor(a3, 16, 64); a3 += __shfl_xor(a3, 32, 64);
    a4 += __shfl_xor(a4, 16, 64); a4 += __shfl_xor(a4, 32, 64);
    a5 += __shfl_xor(a5, 16, 64); a5 += __shfl_xor(a5, 32, 64);
    a6 += __shfl_xor(a6, 16, 64); a6 += __shfl_xor(a6, 32, 64);
    a7 += __shfl_xor(a7, 16, 64); a7 += __shfl_xor(a7, 32, 64);
    if (quarter == 0) {
        uint4 raw = h4[(size_t)n * 16 + ql];
        float s2 = dn * dn;
        float4 bv0 = ((const float4*)b)[ql * 2];
        float4 bv1 = ((const float4*)b)[ql * 2 + 1];
        float o0 = a0 * dn + bf_lo(raw.x) * s2 + bv0.x;
        float o1 = a1 * dn + bf_hi(raw.x) * s2 + bv0.y;
        float o2 = a2 * dn + bf_lo(raw.y) * s2 + bv0.z;
        float o3 = a3 * dn + bf_hi(raw.y) * s2 + bv0.w;
        float o4 = a4 * dn + bf_lo(raw.z) * s2 + bv1.x;
        float o5 = a5 * dn + bf_hi(raw.z) * s2 + bv1.y;
        float o6 = a6 * dn + bf_lo(raw.w) * s2 + bv1.z;
        float o7 = a7 * dn + bf_hi(raw.w) * s2 + bv1.w;
        float4* op = (float4*)(out + (size_t)n * CH + ql * 8);
        float4 w0 = {o0, o1, o2, o3};
        float4 w1 = {o4, o5, o6, o7};
        op[0] = w0;
        op[1] = w1;
        int c0 = ql * 8;
        atomicAdd(&bsum[c0 + 0], o0); atomicAdd(&bsq[c0 + 0], o0 * o0);
        atomicAdd(&bsum[c0 + 1], o1); atomicAdd(&bsq[c0 + 1], o1 * o1);
        atomicAdd(&bsum[c0 + 2], o2); atomicAdd(&bsq[c0 + 2], o2 * o2);
        atomicAdd(&bsum[c0 + 3], o3); atomicAdd(&bsq[c0 + 3], o3 * o3);
        atomicAdd(&bsum[c0 + 4], o4); atomicAdd(&bsq[c0 + 4], o4 * o4);
        atomicAdd(&bsum[c0 + 5], o5); atomicAdd(&bsq[c0 + 5], o5 * o5);
        atomicAdd(&bsum[c0 + 6], o6); atomicAdd(&bsq[c0 + 6], o6 * o6);
        atomicAdd(&bsum[c0 + 7], o7); atomicAdd(&bsq[c0 + 7], o7 * o7);
    }
    __syncthreads();
    float* dst8 = sums8 + (blockIdx.x & 7) * 256;
    atomicAdd(&dst8[t], (t < CH) ? bsum[t] : bsq[t - CH]);
}

__global__ __launch_bounds__(256) void bn_relu_kernel(float* __restrict__ out,
                                                      const float* __restrict__ sums8,
                                                      const float* __restrict__ gamma,
                                                      const float* __restrict__ beta) {
    __shared__ float sc[CH], sh[CH];
    int t = threadIdx.x;
    if (t < CH) {
        float s = 0.0f, q = 0.0f;
#pragma unroll
        for (int k = 0; k < 8; ++k) {
            s += sums8[k * 256 + t];
            q += sums8[k * 256 + CH + t];
        }
        const float invN = 1.0f / (float)N_NODES;
        float mean = s * invN;
        float var = q * invN - mean * mean;
        float scale = gamma[t] * rsqrtf(var + BN_EPS);
        sc[t] = scale;
        sh[t] = beta[t] - mean * scale;
    }
    __syncthreads();
    int i = blockIdx.x * 256 + t;  // float4 index; grid covers exactly N*CH/4
    int c0 = (i & 31) * 4;
    float4 v = ((float4*)out)[i];
    float r0 = v.x * sc[c0] + sh[c0];
    float r1 = v.y * sc[c0 + 1] + sh[c0 + 1];
    float r2 = v.z * sc[c0 + 2] + sh[c0 + 2];
    float r3 = v.w * sc[c0 + 3] + sh[c0 + 3];
    v.x = r0 > 0.0f ? r0 : 0.0f;
    v.y = r1 > 0.0f ? r1 : 0.0f;
    v.z = r2 > 0.0f ? r2 : 0.0f;
    v.w = r3 > 0.0f ? r3 : 0.0f;
    ((float4*)out)[i] = v;
}

extern "C" void kernel_launch(void* const* d_in, const int* in_sizes, int n_in,
                              void* d_out, int out_size, void* d_ws, size_t ws_size,
                              hipStream_t stream) {
    const float* x = (const float*)d_in[0];
    const int* ei = (const int*)d_in[1];
    const float* W = (const float*)d_in[2];
    const float* b = (const float*)d_in[3];
    const float* gamma = (const float*)d_in[4];
    const float* beta = (const float*)d_in[5];
    float* out = (float*)d_out;
    const int* src = ei;
    const int* dst = ei + N_EDGES;
    char* ws = (char*)d_ws;

    unsigned short* hbf = (unsigned short*)ws;
    int* deg = (int*)(ws + 10240000);
    float* sums8 = (float*)(ws + 10400000);
    int* offs = (int*)(ws + 10408192);
    float* dinv = (float*)(ws + 10568192);
    int* bases = (int*)(ws + 10728192);
    uint2* csr64 = (uint2*)(ws + 10728832);

    // zero deg (40000 i32) + sums8 (2048 f32) in one contiguous memset
    hipMemsetAsync(deg, 0, 168192, stream);
    deg_kernel<<<(N_EDGES + 255) / 256, 256, 0, stream>>>(dst, deg);
    scan_a<<<NBLK_SCAN, 256, 0, stream>>>(deg, offs, bases, dinv);
    scan_b<<<1, 256, 0, stream>>>(bases);
    fill_kernel<<<(N_EDGES + 255) / 256, 256, 0, stream>>>(src, dst, bases, dinv, offs, csr64);
    matmul_kernel<<<N_NODES / MM_ROWS, 256, 0, stream>>>(x, W, hbf);
    aggregate_kernel<<<N_NODES / 4, 256, 0, stream>>>(csr64, offs, bases, hbf, dinv, b, out, sums8);
    bn_relu_kernel<<<N_NODES * CH / 4 / 256, 256, 0, stream>>>(out, sums8, gamma, beta);
}